// Round 1
// baseline (1896.041 us; speedup 1.0000x reference)
//
#include <hip/hip_runtime.h>
#include <hip/hip_bf16.h>
#include <cstdint>
#include <cstddef>

// ---------------------------------------------------------------------------
// SparseTransformerLayer on MI355X (gfx950) — v2 (algebraic decomposition)
// N_NODES=50000, N_EDGES=400000, D=256, H=4, HD=64
//
// Key identities exploited:
//   [h_n[idx], h_e] @ W = h_n @ W_top (node table, 50k rows) + h_e @ W_bot
//   sum_e w_e^h * V[e]  = (sum_e w_e^h * [h_n[dst_e], h_e[e]]) @ Wv   (sum w = 1)
//   (agg @ Wv) @ Wo     = agg @ (Wv @ Wo) = agg @ Wcomb (precomputed, per head)
// so V is never materialized per edge and Wo is folded away.
// Pipeline: casts -> weight prep -> CSR -> EN(node QK table) -> EEQ(Q final)
//           -> EEK(K + fused scores) -> aggregate(inputs, per head) ->
//           Wcomb GEMM -> LN1 -> FFN1 -> FFN2 -> LN2
// ---------------------------------------------------------------------------

typedef __bf16 bf16;
typedef bf16 bf16x8 __attribute__((ext_vector_type(8)));
typedef bf16 bf16x4v __attribute__((ext_vector_type(4)));
typedef float f32x4 __attribute__((ext_vector_type(4)));
typedef const uint32_t __attribute__((address_space(1)))* gas_u32p;
typedef uint32_t __attribute__((address_space(3)))* las_u32p;

#define DEV static __device__ __forceinline__

static constexpr int NN = 50000;
static constexpr int NE = 400000;

DEV void async_copy16(const void* g, void* l) {
  __builtin_amdgcn_global_load_lds((gas_u32p)g, (las_u32p)l, 16, 0, 0);
}
DEV float bf2f(bf16 x) { return (float)x; }
DEV bf16  f2bf(float x) { return (bf16)x; }

// ---------------------------------------------------------------------------
// Generic node GEMM: A [M][KT] bf16 (row-clamped), B = WT [Nout][KT] bf16.
// grid = (col_tiles, row_tiles): consecutive blocks share the A row-panel.
// EPI 0: outf = acc (+bias) f32.  EPI 1: outb = bf16(gelu(acc+bias)).
// EPI 2: outb = bf16(acc (+bias)).
// ---------------------------------------------------------------------------
template <int KT, int EPI>
__global__ __launch_bounds__(256, 2) void gemm_node(
    const bf16* __restrict__ A, int M, const bf16* __restrict__ WT,
    const float* __restrict__ bias, int Nout, float* __restrict__ outf,
    bf16* __restrict__ outb) {
  __shared__ bf16 Al[128 * 32];
  __shared__ bf16 Bl[128 * 32];
  const int tid = threadIdx.x;
  const int n0 = blockIdx.x * 128;
  const int m0 = blockIdx.y * 128;
  const bf16* ab[2];
  const bf16* bb[2];
#pragma unroll
  for (int p = 0; p < 2; ++p) {
    int c = tid + 256 * p;
    int row = c >> 2;
    int c8 = (c & 3) * 8;
    int rg = m0 + row;
    if (rg > M - 1) rg = M - 1;  // clamp; stores are guarded
    ab[p] = A + (size_t)rg * KT + c8;
    bb[p] = WT + (size_t)(n0 + row) * KT + c8;
  }
  const int wv = tid >> 6, lane = tid & 63;
  const int quad = lane >> 4, l16 = lane & 15;
  const int wrow = (wv >> 1) * 64, wcol = (wv & 1) * 64;
  f32x4 acc[4][4] = {};
  for (int k0 = 0; k0 < KT; k0 += 32) {
    if (k0) __syncthreads();
#pragma unroll
    for (int p = 0; p < 2; ++p) {
      async_copy16(ab[p] + k0, &Al[(tid + 256 * p) * 8]);
      async_copy16(bb[p] + k0, &Bl[(tid + 256 * p) * 8]);
    }
    __syncthreads();
    bf16x8 af[4], bfr[4];
#pragma unroll
    for (int t = 0; t < 4; ++t)
      af[t] = *(const bf16x8*)&Al[(wrow + t * 16 + l16) * 32 + quad * 8];
#pragma unroll
    for (int t = 0; t < 4; ++t)
      bfr[t] = *(const bf16x8*)&Bl[(wcol + t * 16 + l16) * 32 + quad * 8];
#pragma unroll
    for (int mt = 0; mt < 4; ++mt)
#pragma unroll
      for (int nt = 0; nt < 4; ++nt)
        acc[mt][nt] = __builtin_amdgcn_mfma_f32_16x16x32_bf16(
            af[mt], bfr[nt], acc[mt][nt], 0, 0, 0);
  }
#pragma unroll
  for (int nt = 0; nt < 4; ++nt) {
    int col = n0 + wcol + nt * 16 + l16;
    float bv = bias ? bias[col] : 0.f;
#pragma unroll
    for (int mt = 0; mt < 4; ++mt)
#pragma unroll
      for (int r = 0; r < 4; ++r) {
        int row = m0 + wrow + mt * 16 + quad * 4 + r;
        if (row < M) {
          float v = acc[mt][nt][r] + bv;
          if (EPI == 0)
            outf[(size_t)row * Nout + col] = v;
          else if (EPI == 1)
            outb[(size_t)row * Nout + col] =
                f2bf(0.5f * v * (1.f + erff(v * 0.70710678118654752f)));
          else
            outb[(size_t)row * Nout + col] = f2bf(v);
        }
      }
  }
}

// ---------------------------------------------------------------------------
// EEQ: Q_edge = h_e @ WeT[0:256] ; epilogue adds Wq_b + ENf[src[row]][col]
// (node part, f32) and writes final Q bf16 [NE][256].
// ---------------------------------------------------------------------------
__global__ __launch_bounds__(256, 2) void gemm_eeq(
    const bf16* __restrict__ he, const bf16* __restrict__ WT,
    const float* __restrict__ bias, const int* __restrict__ src,
    const float* __restrict__ ENf, bf16* __restrict__ Qout) {
  __shared__ bf16 Al[128 * 32];
  __shared__ bf16 Bl[128 * 32];
  const int tid = threadIdx.x;
  const int n0 = blockIdx.x * 128;
  const int m0 = blockIdx.y * 128;
  const bf16* ab[2];
  const bf16* bb[2];
#pragma unroll
  for (int p = 0; p < 2; ++p) {
    int c = tid + 256 * p;
    int row = c >> 2;
    int c8 = (c & 3) * 8;
    ab[p] = he + (size_t)(m0 + row) * 256 + c8;
    bb[p] = WT + (size_t)(n0 + row) * 256 + c8;
  }
  const int wv = tid >> 6, lane = tid & 63;
  const int quad = lane >> 4, l16 = lane & 15;
  const int wrow = (wv >> 1) * 64, wcol = (wv & 1) * 64;
  f32x4 acc[4][4] = {};
  for (int k0 = 0; k0 < 256; k0 += 32) {
    if (k0) __syncthreads();
#pragma unroll
    for (int p = 0; p < 2; ++p) {
      async_copy16(ab[p] + k0, &Al[(tid + 256 * p) * 8]);
      async_copy16(bb[p] + k0, &Bl[(tid + 256 * p) * 8]);
    }
    __syncthreads();
    bf16x8 af[4], bfr[4];
#pragma unroll
    for (int t = 0; t < 4; ++t)
      af[t] = *(const bf16x8*)&Al[(wrow + t * 16 + l16) * 32 + quad * 8];
#pragma unroll
    for (int t = 0; t < 4; ++t)
      bfr[t] = *(const bf16x8*)&Bl[(wcol + t * 16 + l16) * 32 + quad * 8];
#pragma unroll
    for (int mt = 0; mt < 4; ++mt)
#pragma unroll
      for (int nt = 0; nt < 4; ++nt)
        acc[mt][nt] = __builtin_amdgcn_mfma_f32_16x16x32_bf16(
            af[mt], bfr[nt], acc[mt][nt], 0, 0, 0);
  }
  float bv[4];
#pragma unroll
  for (int nt = 0; nt < 4; ++nt) bv[nt] = bias[n0 + wcol + nt * 16 + l16];
#pragma unroll
  for (int mt = 0; mt < 4; ++mt)
#pragma unroll
    for (int r = 0; r < 4; ++r) {
      int row = m0 + wrow + mt * 16 + quad * 4 + r;
      int s = src[row];
      const float* en = ENf + (size_t)s * 512;
#pragma unroll
      for (int nt = 0; nt < 4; ++nt) {
        int col = n0 + wcol + nt * 16 + l16;
        Qout[(size_t)row * 256 + col] = f2bf(acc[mt][nt][r] + bv[nt] + en[col]);
      }
    }
}

// ---------------------------------------------------------------------------
// EEK: K_edge = h_e @ WeT[256:512]; epilogue builds K = acc + Wkv_b[col] +
// ENf[dst[row]][256+col], dots with materialized Q (wave's 64 cols == one
// head), shuffle-reduces, writes scores [NE][4].
// ---------------------------------------------------------------------------
__global__ __launch_bounds__(256, 2) void gemm_eek(
    const bf16* __restrict__ he, const bf16* __restrict__ WT,
    const float* __restrict__ bias, const int* __restrict__ dstp,
    const float* __restrict__ ENf, const bf16* __restrict__ Qbf,
    float* __restrict__ scores) {
  __shared__ bf16 Al[128 * 32];
  __shared__ bf16 Bl[128 * 32];
  const int tid = threadIdx.x;
  const int n0 = blockIdx.x * 128;
  const int m0 = blockIdx.y * 128;
  const bf16* ab[2];
  const bf16* bb[2];
#pragma unroll
  for (int p = 0; p < 2; ++p) {
    int c = tid + 256 * p;
    int row = c >> 2;
    int c8 = (c & 3) * 8;
    ab[p] = he + (size_t)(m0 + row) * 256 + c8;
    bb[p] = WT + (size_t)(n0 + row) * 256 + c8;
  }
  const int wv = tid >> 6, lane = tid & 63;
  const int quad = lane >> 4, l16 = lane & 15;
  const int wrow = (wv >> 1) * 64, wcol = (wv & 1) * 64;
  f32x4 acc[4][4] = {};
  for (int k0 = 0; k0 < 256; k0 += 32) {
    if (k0) __syncthreads();
#pragma unroll
    for (int p = 0; p < 2; ++p) {
      async_copy16(ab[p] + k0, &Al[(tid + 256 * p) * 8]);
      async_copy16(bb[p] + k0, &Bl[(tid + 256 * p) * 8]);
    }
    __syncthreads();
    bf16x8 af[4], bfr[4];
#pragma unroll
    for (int t = 0; t < 4; ++t)
      af[t] = *(const bf16x8*)&Al[(wrow + t * 16 + l16) * 32 + quad * 8];
#pragma unroll
    for (int t = 0; t < 4; ++t)
      bfr[t] = *(const bf16x8*)&Bl[(wcol + t * 16 + l16) * 32 + quad * 8];
#pragma unroll
    for (int mt = 0; mt < 4; ++mt)
#pragma unroll
      for (int nt = 0; nt < 4; ++nt)
        acc[mt][nt] = __builtin_amdgcn_mfma_f32_16x16x32_bf16(
            af[mt], bfr[nt], acc[mt][nt], 0, 0, 0);
  }
  float bv[4];
#pragma unroll
  for (int nt = 0; nt < 4; ++nt) bv[nt] = bias[n0 + wcol + nt * 16 + l16];
  const int head = (n0 + wcol) >> 6;
#pragma unroll
  for (int mt = 0; mt < 4; ++mt)
#pragma unroll
    for (int r = 0; r < 4; ++r) {
      int row = m0 + wrow + mt * 16 + quad * 4 + r;
      int d = dstp[row];
      const float* en = ENf + (size_t)d * 512 + 256;
      const bf16* qr = Qbf + (size_t)row * 256;
      float part = 0.f;
#pragma unroll
      for (int nt = 0; nt < 4; ++nt) {
        int col = n0 + wcol + nt * 16 + l16;
        float kv = acc[mt][nt][r] + bv[nt] + en[col];
        part += kv * bf2f(qr[col]);
      }
      part += __shfl_xor(part, 1);
      part += __shfl_xor(part, 2);
      part += __shfl_xor(part, 4);
      part += __shfl_xor(part, 8);
      if (l16 == 0) scores[(size_t)row * 4 + head] = part * 0.125f;  // /sqrt(64)
    }
}

// --------------------------- utility kernels -------------------------------
__global__ __launch_bounds__(256) void cast_bf16(const float* __restrict__ in,
                                                 bf16* __restrict__ out, int n) {
  int i = (blockIdx.x * 256 + threadIdx.x) * 4;
  if (i < n) {
    float4 v = *(const float4*)(in + i);
    bf16x4v o = {f2bf(v.x), f2bf(v.y), f2bf(v.z), f2bf(v.w)};
    *(bf16x4v*)(out + i) = o;
  }
}

// W [K][N] f32  ->  WT [N][K] bf16
__global__ __launch_bounds__(256) void transpose_cast(
    const float* __restrict__ W, bf16* __restrict__ WT, int K, int N) {
  int i = blockIdx.x * 256 + threadIdx.x;
  if (i < K * N) {
    int k = i / N, n = i - k * N;
    WT[(size_t)n * K + k] = f2bf(W[i]);
  }
}

// WnT[n][k]: node-half of [Wq | Wkv] QK cols; WeT[n][k]: edge-half.
// n<256 -> Q col n ; n>=256 -> K col n-256.
__global__ __launch_bounds__(256) void build_wnet(
    const float* __restrict__ Wq, const float* __restrict__ Wkv,
    bf16* __restrict__ WnT, bf16* __restrict__ WeT) {
  int n = blockIdx.x, k = threadIdx.x;
  float vn, ve;
  if (n < 256) {
    vn = Wq[(size_t)k * 256 + n];
    ve = Wq[(size_t)(256 + k) * 256 + n];
  } else {
    vn = Wkv[(size_t)k * 512 + (n - 256)];
    ve = Wkv[(size_t)(256 + k) * 512 + (n - 256)];
  }
  WnT[(size_t)n * 256 + k] = f2bf(vn);
  WeT[(size_t)n * 256 + k] = f2bf(ve);
}

// Wcomb[h*512+i][j] = sum_m Wkv[i][256+h*64+m] * Wo[h*64+m][j]  (per-head
// V-projection folded with Wo).  Stored transposed: WcombT [256][2048] bf16.
// Also bias_vo[j] = sum_t Wkv_b[256+t]*Wo[t][j] + Wo_b[j].
__global__ __launch_bounds__(256) void build_wcomb(
    const float* __restrict__ Wkv, const float* __restrict__ Wkv_b,
    const float* __restrict__ Wo, const float* __restrict__ Wo_b,
    bf16* __restrict__ WcombT, float* __restrict__ bias_vo) {
  int j = blockIdx.x, t = threadIdx.x;
  __shared__ float wo[256];
  wo[t] = Wo[(size_t)t * 256 + j];
  __syncthreads();
#pragma unroll
  for (int p = 0; p < 8; ++p) {
    int idx = p * 256 + t;           // 0..2047
    int h = idx >> 9, i = idx & 511;
    const float* wrow = Wkv + (size_t)i * 512 + 256 + h * 64;
    const float* wob = wo + h * 64;
    float s = 0.f;
#pragma unroll 8
    for (int m = 0; m < 64; ++m) s += wrow[m] * wob[m];
    WcombT[(size_t)j * 2048 + idx] = f2bf(s);
  }
  float bs = Wkv_b[256 + t] * wo[t];
#pragma unroll
  for (int o = 32; o; o >>= 1) bs += __shfl_xor(bs, o);
  __shared__ float red[4];
  int wv = t >> 6, lane = t & 63;
  if (lane == 0) red[wv] = bs;
  __syncthreads();
  if (t == 0) bias_vo[j] = red[0] + red[1] + red[2] + red[3] + Wo_b[j];
}

__global__ __launch_bounds__(256) void count_deg(const int* __restrict__ src,
                                                 int* __restrict__ deg, int nE) {
  int e = blockIdx.x * 256 + threadIdx.x;
  if (e < nE) atomicAdd(&deg[src[e]], 1);
}

__global__ __launch_bounds__(256) void scan_offs(const int* __restrict__ deg,
                                                 int* __restrict__ offs,
                                                 int* __restrict__ cursor,
                                                 int nN) {
  __shared__ int part[256];
  int tid = threadIdx.x;
  int per = (nN + 255) >> 8;
  int lo = tid * per, hi = lo + per;
  if (hi > nN) hi = nN;
  int sm = 0;
  for (int i = lo; i < hi; ++i) sm += deg[i];
  part[tid] = sm;
  __syncthreads();
  if (tid == 0) {
    int run = 0;
    for (int i = 0; i < 256; ++i) {
      int v = part[i];
      part[i] = run;
      run += v;
    }
  }
  __syncthreads();
  int run = part[tid];
  for (int i = lo; i < hi; ++i) {
    offs[i] = run;
    cursor[i] = run;
    run += deg[i];
  }
  if (tid == 255) offs[nN] = run;
}

__global__ __launch_bounds__(256) void scatter_edges(const int* __restrict__ src,
                                                     int* __restrict__ cursor,
                                                     int* __restrict__ eperm,
                                                     int nE) {
  int e = blockIdx.x * 256 + threadIdx.x;
  if (e < nE) {
    int p = atomicAdd(&cursor[src[e]], 1);
    eperm[p] = e;
  }
}

// Per-node segment softmax + PER-HEAD weighted input aggregation.
// aggH[n][h*512 + c]     = sum_e w_e^h * h_n[dst_e][c]   (c<256)
// aggH[n][h*512 + 256+c] = sum_e w_e^h * h_e[e][c]
__global__ __launch_bounds__(256) void aggregate(
    const int* __restrict__ offs, const int* __restrict__ eperm,
    const int* __restrict__ dstp, const float* __restrict__ scores,
    const bf16* __restrict__ hn, const bf16* __restrict__ he,
    bf16* __restrict__ aggH) {
  int n = blockIdx.x;
  int s = offs[n];
  int deg = offs[n + 1] - s;
  int tid = threadIdx.x, wv = tid >> 6, lane = tid & 63;
  __shared__ float mdl[4], dnl[4];
  float mx = -3.4e38f;
  for (int i = lane; i < deg; i += 64) {
    int e = eperm[s + i];
    mx = fmaxf(mx, scores[(size_t)e * 4 + wv]);
  }
#pragma unroll
  for (int o = 32; o; o >>= 1) mx = fmaxf(mx, __shfl_xor(mx, o));
  float sm = 0.f;
  for (int i = lane; i < deg; i += 64) {
    int e = eperm[s + i];
    sm += expf(scores[(size_t)e * 4 + wv] - mx);
  }
#pragma unroll
  for (int o = 32; o; o >>= 1) sm += __shfl_xor(sm, o);
  if (lane == 0) {
    mdl[wv] = mx;
    dnl[wv] = sm;
  }
  __syncthreads();
  float m[4], rd[4];
#pragma unroll
  for (int h = 0; h < 4; ++h) {
    m[h] = mdl[h];
    rd[h] = dnl[h] > 0.f ? 1.f / dnl[h] : 0.f;
  }
  float accn[4] = {}, acce[4] = {};
  for (int i = 0; i < deg; ++i) {
    int e = eperm[s + i];
    int d = dstp[e];
    f32x4 sc = *(const f32x4*)(scores + (size_t)e * 4);
    float w[4];
#pragma unroll
    for (int h = 0; h < 4; ++h) w[h] = expf(sc[h] - m[h]) * rd[h];
    float xn = bf2f(hn[(size_t)d * 256 + tid]);
    float xe = bf2f(he[(size_t)e * 256 + tid]);
#pragma unroll
    for (int h = 0; h < 4; ++h) {
      accn[h] += w[h] * xn;
      acce[h] += w[h] * xe;
    }
  }
  bf16* out = aggH + (size_t)n * 2048;
#pragma unroll
  for (int h = 0; h < 4; ++h) {
    out[h * 512 + tid] = f2bf(accn[h]);
    out[h * 512 + 256 + tid] = f2bf(acce[h]);
  }
}

// y = LN(x1 + x2) * g + b ; optional f32 and bf16 outputs. block = row (256).
__global__ __launch_bounds__(256) void ln_kernel(
    const float* __restrict__ x1, const float* __restrict__ x2,
    const float* __restrict__ g, const float* __restrict__ b,
    float* __restrict__ outf, bf16* __restrict__ outb) {
  int n = blockIdx.x, tid = threadIdx.x;
  float x = x1[(size_t)n * 256 + tid] + x2[(size_t)n * 256 + tid];
  float s = x, s2 = x * x;
#pragma unroll
  for (int o = 32; o; o >>= 1) {
    s += __shfl_xor(s, o);
    s2 += __shfl_xor(s2, o);
  }
  __shared__ float ls[4], ls2[4];
  int wv = tid >> 6, lane = tid & 63;
  if (lane == 0) {
    ls[wv] = s;
    ls2[wv] = s2;
  }
  __syncthreads();
  s = ls[0] + ls[1] + ls[2] + ls[3];
  s2 = ls2[0] + ls2[1] + ls2[2] + ls2[3];
  float mu = s * (1.f / 256.f);
  float var = s2 * (1.f / 256.f) - mu * mu;
  float y = (x - mu) * rsqrtf(var + 1e-5f) * g[tid] + b[tid];
  if (outf) outf[(size_t)n * 256 + tid] = y;
  if (outb) outb[(size_t)n * 256 + tid] = f2bf(y);
}

// --------------------------- workspace layout ------------------------------
static constexpr size_t OFF_HN    = 0;                     // 50000*256 bf16
static constexpr size_t OFF_HE    = 25600000;              // 400000*256 bf16
static constexpr size_t OFF_WNT   = 230400000;             // 512x256 bf16
static constexpr size_t OFF_WET   = 230662144;             // 512x256 bf16
static constexpr size_t OFF_WCT   = 230924288;             // 256x2048 bf16
static constexpr size_t OFF_W1T   = 231972864;             // 1024x256 bf16
static constexpr size_t OFF_W2T   = 232497152;             // 256x1024 bf16
static constexpr size_t OFF_BVO   = 233021440;             // 256 f32
static constexpr size_t OFF_SC    = 233022464;             // 400000*4 f32
static constexpr size_t OFF_DEG   = 239422464;             // 50000 i32
static constexpr size_t OFF_OFFS  = 239622464;             // 50001 i32 (padded)
static constexpr size_t OFF_CUR   = 239822528;             // 50000 i32
static constexpr size_t OFF_EPERM = 240022528;             // 400000 i32
static constexpr size_t OFF_ENF   = 241622528;             // 50000*512 f32
static constexpr size_t OFF_Q     = 344022528;             // 400000*256 bf16
// aliases (strictly ordered by stream dependencies):
static constexpr size_t OFF_AGGH  = OFF_Q;                 // 50000*2048 bf16 (Q dead after EEK)
static constexpr size_t OFF_TMP   = OFF_HE;                // 50000*256 f32 (he dead after aggregate)
static constexpr size_t OFF_H1F   = OFF_HE + 51200000;     // 50000*256 f32
static constexpr size_t OFF_H1B   = OFF_HE + 102400000;    // 50000*256 bf16
static constexpr size_t OFF_TMP2  = OFF_HE + 128000000;    // 50000*256 f32
static constexpr size_t OFF_FFM   = OFF_Q;                 // 50000*1024 bf16 (aggH dead after VO)
// total need: OFF_Q + 204800000 = 548,822,528 bytes

extern "C" void kernel_launch(void* const* d_in, const int* in_sizes, int n_in,
                              void* d_out, int out_size, void* d_ws,
                              size_t ws_size, hipStream_t stream) {
  const float* h_n = (const float*)d_in[0];
  const float* h_e = (const float*)d_in[1];
  const int* eidx = (const int*)d_in[2];
  const int* src = eidx;
  const int* dst = eidx + NE;
  const float* Wq_w = (const float*)d_in[3];
  const float* Wq_b = (const float*)d_in[4];
  const float* Wkv_w = (const float*)d_in[5];
  const float* Wkv_b = (const float*)d_in[6];
  const float* Wo_w = (const float*)d_in[7];
  const float* Wo_b = (const float*)d_in[8];
  const float* ln1_g = (const float*)d_in[9];
  const float* ln1_b = (const float*)d_in[10];
  const float* f1_w = (const float*)d_in[11];
  const float* f1_b = (const float*)d_in[12];
  const float* f2_w = (const float*)d_in[13];
  const float* f2_b = (const float*)d_in[14];
  const float* ln2_g = (const float*)d_in[15];
  const float* ln2_b = (const float*)d_in[16];

  uint8_t* ws = (uint8_t*)d_ws;
  bf16* hn_bf = (bf16*)(ws + OFF_HN);
  bf16* he_bf = (bf16*)(ws + OFF_HE);
  bf16* WnT = (bf16*)(ws + OFF_WNT);
  bf16* WeT = (bf16*)(ws + OFF_WET);
  bf16* WcombT = (bf16*)(ws + OFF_WCT);
  bf16* W1T = (bf16*)(ws + OFF_W1T);
  bf16* W2T = (bf16*)(ws + OFF_W2T);
  float* bias_vo = (float*)(ws + OFF_BVO);
  float* scores = (float*)(ws + OFF_SC);
  int* deg = (int*)(ws + OFF_DEG);
  int* offs = (int*)(ws + OFF_OFFS);
  int* cursor = (int*)(ws + OFF_CUR);
  int* eperm = (int*)(ws + OFF_EPERM);
  float* ENf = (float*)(ws + OFF_ENF);
  bf16* Qbf = (bf16*)(ws + OFF_Q);
  bf16* aggH = (bf16*)(ws + OFF_AGGH);
  float* tmp = (float*)(ws + OFF_TMP);
  float* h1f = (float*)(ws + OFF_H1F);
  bf16* h1b = (bf16*)(ws + OFF_H1B);
  float* tmp2 = (float*)(ws + OFF_TMP2);
  bf16* ffm = (bf16*)(ws + OFF_FFM);

  // 1. casts + weight prep
  cast_bf16<<<12500, 256, 0, stream>>>(h_n, hn_bf, NN * 256);
  cast_bf16<<<100000, 256, 0, stream>>>(h_e, he_bf, NE * 256);
  build_wnet<<<512, 256, 0, stream>>>(Wq_w, Wkv_w, WnT, WeT);
  build_wcomb<<<256, 256, 0, stream>>>(Wkv_w, Wkv_b, Wo_w, Wo_b, WcombT,
                                       bias_vo);
  transpose_cast<<<1024, 256, 0, stream>>>(f1_w, W1T, 256, 1024);
  transpose_cast<<<1024, 256, 0, stream>>>(f2_w, W2T, 1024, 256);

  // 2. CSR over src
  hipMemsetAsync(deg, 0, NN * sizeof(int), stream);
  count_deg<<<1563, 256, 0, stream>>>(src, deg, NE);
  scan_offs<<<1, 256, 0, stream>>>(deg, offs, cursor, NN);
  scatter_edges<<<1563, 256, 0, stream>>>(src, cursor, eperm, NE);

  // 3. node QK table (f32), then edge Q (final, bf16), then edge K + scores
  gemm_node<256, 0><<<dim3(4, 391), 256, 0, stream>>>(hn_bf, NN, WnT, nullptr,
                                                      512, ENf, nullptr);
  gemm_eeq<<<dim3(2, 3125), 256, 0, stream>>>(he_bf, WeT, Wq_b, src, ENf, Qbf);
  gemm_eek<<<dim3(2, 3125), 256, 0, stream>>>(he_bf, WeT + 256 * 256, Wkv_b,
                                              dst, ENf, Qbf, scores);

  // 4. segment softmax + per-head weighted input aggregation
  aggregate<<<NN, 256, 0, stream>>>(offs, eperm, dst, scores, hn_bf, he_bf,
                                    aggH);

  // 5. folded V-projection + Wo (one K=2048 GEMM) + LN1
  gemm_node<2048, 0><<<dim3(2, 391), 256, 0, stream>>>(aggH, NN, WcombT,
                                                       bias_vo, 256, tmp,
                                                       nullptr);
  ln_kernel<<<NN, 256, 0, stream>>>(h_n, tmp, ln1_g, ln1_b, h1f, h1b);

  // 6. FFN + LN2
  gemm_node<256, 1><<<dim3(8, 391), 256, 0, stream>>>(h1b, NN, W1T, f1_b, 1024,
                                                      nullptr, ffm);
  gemm_node<1024, 0><<<dim3(2, 391), 256, 0, stream>>>(ffm, NN, W2T, f2_b, 256,
                                                       tmp2, nullptr);
  ln_kernel<<<NN, 256, 0, stream>>>(h1f, tmp2, ln2_g, ln2_b, (float*)d_out,
                                    nullptr);
}

// Round 2
// 1697.139 us; speedup vs baseline: 1.1172x; 1.1172x over previous
//
#include <hip/hip_runtime.h>
#include <hip/hip_bf16.h>
#include <cstdint>
#include <cstddef>

// ---------------------------------------------------------------------------
// SparseTransformerLayer on MI355X (gfx950) — v3
// N_NODES=50000, N_EDGES=400000, D=256, H=4, HD=64
//
// v3 changes vs v2:
//  * gemm_qk: fused Q/K edge GEMM sharing one h_e staging; scores formed in
//    registers; Q never materialized in HBM (saves 410 MB + one staging pass)
//  * h_e cast into CSR-permuted order -> all edge streams are sequential,
//    src-gathers of the EN table become sorted
//  * aggregate: per-(edge,head) softmax weight computed ONCE into LDS
//    (1.6M expf total, was 410M) then broadcast to the 256-wide FMA loop
// ---------------------------------------------------------------------------

typedef __bf16 bf16;
typedef bf16 bf16x8 __attribute__((ext_vector_type(8)));
typedef bf16 bf16x4v __attribute__((ext_vector_type(4)));
typedef float f32x4 __attribute__((ext_vector_type(4)));
typedef const uint32_t __attribute__((address_space(1)))* gas_u32p;
typedef uint32_t __attribute__((address_space(3)))* las_u32p;

#define DEV static __device__ __forceinline__

static constexpr int NN = 50000;
static constexpr int NE = 400000;

DEV void async_copy16(const void* g, void* l) {
  __builtin_amdgcn_global_load_lds((gas_u32p)g, (las_u32p)l, 16, 0, 0);
}
DEV float bf2f(bf16 x) { return (float)x; }
DEV bf16  f2bf(float x) { return (bf16)x; }

// ---------------------------------------------------------------------------
// Generic node GEMM: A [M][KT] bf16 (row-clamped), B = WT [Nout][KT] bf16.
// grid = (col_tiles, row_tiles): consecutive blocks share the A row-panel.
// EPI 0: outf = acc (+bias) f32.  EPI 1: outb = bf16(gelu(acc+bias)).
// ---------------------------------------------------------------------------
template <int KT, int EPI>
__global__ __launch_bounds__(256, 2) void gemm_node(
    const bf16* __restrict__ A, int M, const bf16* __restrict__ WT,
    const float* __restrict__ bias, int Nout, float* __restrict__ outf,
    bf16* __restrict__ outb) {
  __shared__ bf16 Al[128 * 32];
  __shared__ bf16 Bl[128 * 32];
  const int tid = threadIdx.x;
  const int n0 = blockIdx.x * 128;
  const int m0 = blockIdx.y * 128;
  const bf16* ab[2];
  const bf16* bb[2];
#pragma unroll
  for (int p = 0; p < 2; ++p) {
    int c = tid + 256 * p;
    int row = c >> 2;
    int c8 = (c & 3) * 8;
    int rg = m0 + row;
    if (rg > M - 1) rg = M - 1;  // clamp; stores are guarded
    ab[p] = A + (size_t)rg * KT + c8;
    bb[p] = WT + (size_t)(n0 + row) * KT + c8;
  }
  const int wv = tid >> 6, lane = tid & 63;
  const int quad = lane >> 4, l16 = lane & 15;
  const int wrow = (wv >> 1) * 64, wcol = (wv & 1) * 64;
  f32x4 acc[4][4] = {};
  for (int k0 = 0; k0 < KT; k0 += 32) {
    if (k0) __syncthreads();
#pragma unroll
    for (int p = 0; p < 2; ++p) {
      async_copy16(ab[p] + k0, &Al[(tid + 256 * p) * 8]);
      async_copy16(bb[p] + k0, &Bl[(tid + 256 * p) * 8]);
    }
    __syncthreads();
    bf16x8 af[4], bfr[4];
#pragma unroll
    for (int t = 0; t < 4; ++t)
      af[t] = *(const bf16x8*)&Al[(wrow + t * 16 + l16) * 32 + quad * 8];
#pragma unroll
    for (int t = 0; t < 4; ++t)
      bfr[t] = *(const bf16x8*)&Bl[(wcol + t * 16 + l16) * 32 + quad * 8];
#pragma unroll
    for (int mt = 0; mt < 4; ++mt)
#pragma unroll
      for (int nt = 0; nt < 4; ++nt)
        acc[mt][nt] = __builtin_amdgcn_mfma_f32_16x16x32_bf16(
            af[mt], bfr[nt], acc[mt][nt], 0, 0, 0);
  }
#pragma unroll
  for (int nt = 0; nt < 4; ++nt) {
    int col = n0 + wcol + nt * 16 + l16;
    float bv = bias ? bias[col] : 0.f;
#pragma unroll
    for (int mt = 0; mt < 4; ++mt)
#pragma unroll
      for (int r = 0; r < 4; ++r) {
        int row = m0 + wrow + mt * 16 + quad * 4 + r;
        if (row < M) {
          float v = acc[mt][nt][r] + bv;
          if (EPI == 0)
            outf[(size_t)row * Nout + col] = v;
          else
            outb[(size_t)row * Nout + col] =
                f2bf(0.5f * v * (1.f + erff(v * 0.70710678118654752f)));
        }
      }
  }
}

// ---------------------------------------------------------------------------
// Fused Q/K edge GEMM + scores. A = he (CSR-permuted, sequential rows),
// Bq = WeT[0:256] (Q cols), Bk = WeT[256:512] (K cols). One A staging feeds
// both GEMMs. Epilogue: q = accq + Wq_b + ENf[sp[row]][col],
// k = acck + Wkv_b + ENf[dp[row]][256+col]; per-head 64-col dot ->
// scores[row][head]. Q/K never hit HBM. grid (2 col-tiles, 3125 row-tiles);
// wave's 64 cols == one head.
// ---------------------------------------------------------------------------
__global__ __launch_bounds__(256, 2) void gemm_qk(
    const bf16* __restrict__ he, const bf16* __restrict__ WTq,
    const bf16* __restrict__ WTk, const float* __restrict__ bq,
    const float* __restrict__ bk, const int* __restrict__ sp,
    const int* __restrict__ dp, const float* __restrict__ ENf,
    float* __restrict__ scores) {
  __shared__ bf16 Al[128 * 32];
  __shared__ bf16 Bq[128 * 32];
  __shared__ bf16 Bk[128 * 32];
  const int tid = threadIdx.x;
  const int n0 = blockIdx.x * 128;
  const int m0 = blockIdx.y * 128;
  const bf16* ab[2];
  const bf16* bqp[2];
  const bf16* bkp[2];
#pragma unroll
  for (int p = 0; p < 2; ++p) {
    int c = tid + 256 * p;
    int row = c >> 2;
    int c8 = (c & 3) * 8;
    ab[p] = he + (size_t)(m0 + row) * 256 + c8;
    bqp[p] = WTq + (size_t)(n0 + row) * 256 + c8;
    bkp[p] = WTk + (size_t)(n0 + row) * 256 + c8;
  }
  const int wv = tid >> 6, lane = tid & 63;
  const int quad = lane >> 4, l16 = lane & 15;
  const int wrow = (wv >> 1) * 64, wcol = (wv & 1) * 64;
  f32x4 aq[4][4] = {};
  f32x4 ak[4][4] = {};
  for (int k0 = 0; k0 < 256; k0 += 32) {
    if (k0) __syncthreads();
#pragma unroll
    for (int p = 0; p < 2; ++p) {
      async_copy16(ab[p] + k0, &Al[(tid + 256 * p) * 8]);
      async_copy16(bqp[p] + k0, &Bq[(tid + 256 * p) * 8]);
      async_copy16(bkp[p] + k0, &Bk[(tid + 256 * p) * 8]);
    }
    __syncthreads();
    bf16x8 af[4];
#pragma unroll
    for (int t = 0; t < 4; ++t)
      af[t] = *(const bf16x8*)&Al[(wrow + t * 16 + l16) * 32 + quad * 8];
#pragma unroll
    for (int nt = 0; nt < 4; ++nt) {
      bf16x8 fq = *(const bf16x8*)&Bq[(wcol + nt * 16 + l16) * 32 + quad * 8];
#pragma unroll
      for (int mt = 0; mt < 4; ++mt)
        aq[mt][nt] = __builtin_amdgcn_mfma_f32_16x16x32_bf16(af[mt], fq,
                                                             aq[mt][nt], 0, 0, 0);
      bf16x8 fk = *(const bf16x8*)&Bk[(wcol + nt * 16 + l16) * 32 + quad * 8];
#pragma unroll
      for (int mt = 0; mt < 4; ++mt)
        ak[mt][nt] = __builtin_amdgcn_mfma_f32_16x16x32_bf16(af[mt], fk,
                                                             ak[mt][nt], 0, 0, 0);
    }
  }
  float bvq[4], bvk[4];
#pragma unroll
  for (int nt = 0; nt < 4; ++nt) {
    int col = n0 + wcol + nt * 16 + l16;
    bvq[nt] = bq[col];
    bvk[nt] = bk[col];
  }
  const int head = (n0 + wcol) >> 6;
#pragma unroll
  for (int mt = 0; mt < 4; ++mt)
#pragma unroll
    for (int r = 0; r < 4; ++r) {
      int row = m0 + wrow + mt * 16 + quad * 4 + r;
      int s_ = sp[row], d_ = dp[row];
      const float* eq = ENf + (size_t)s_ * 512;
      const float* ek = ENf + (size_t)d_ * 512 + 256;
      float part = 0.f;
#pragma unroll
      for (int nt = 0; nt < 4; ++nt) {
        int col = n0 + wcol + nt * 16 + l16;
        float qv = aq[mt][nt][r] + bvq[nt] + eq[col];
        float kv = ak[mt][nt][r] + bvk[nt] + ek[col];
        part += qv * kv;
      }
      part += __shfl_xor(part, 1);
      part += __shfl_xor(part, 2);
      part += __shfl_xor(part, 4);
      part += __shfl_xor(part, 8);
      if (l16 == 0) scores[(size_t)row * 4 + head] = part * 0.125f;  // /sqrt(64)
    }
}

// --------------------------- utility kernels -------------------------------
__global__ __launch_bounds__(256) void cast_bf16(const float* __restrict__ in,
                                                 bf16* __restrict__ out, int n) {
  int i = (blockIdx.x * 256 + threadIdx.x) * 4;
  if (i < n) {
    float4 v = *(const float4*)(in + i);
    bf16x4v o = {f2bf(v.x), f2bf(v.y), f2bf(v.z), f2bf(v.w)};
    *(bf16x4v*)(out + i) = o;
  }
}

// h_e f32 -> he_bf bf16 in CSR-permuted order: out[p] = cast(in[eperm[p]]).
// block = 4 rows.
__global__ __launch_bounds__(256) void cast_he_perm(
    const float* __restrict__ in, const int* __restrict__ eperm,
    bf16* __restrict__ out) {
  int p = blockIdx.x * 4 + (threadIdx.x >> 6);
  int c4 = (threadIdx.x & 63) * 4;
  int e = eperm[p];
  float4 v = *(const float4*)(in + (size_t)e * 256 + c4);
  bf16x4v o = {f2bf(v.x), f2bf(v.y), f2bf(v.z), f2bf(v.w)};
  *(bf16x4v*)(out + (size_t)p * 256 + c4) = o;
}

__global__ __launch_bounds__(256) void perm_sd(const int* __restrict__ src,
                                               const int* __restrict__ dst,
                                               const int* __restrict__ eperm,
                                               int* __restrict__ sp,
                                               int* __restrict__ dp, int nE) {
  int p = blockIdx.x * 256 + threadIdx.x;
  if (p < nE) {
    int e = eperm[p];
    sp[p] = src[e];
    dp[p] = dst[e];
  }
}

// W [K][N] f32  ->  WT [N][K] bf16
__global__ __launch_bounds__(256) void transpose_cast(
    const float* __restrict__ W, bf16* __restrict__ WT, int K, int N) {
  int i = blockIdx.x * 256 + threadIdx.x;
  if (i < K * N) {
    int k = i / N, n = i - k * N;
    WT[(size_t)n * K + k] = f2bf(W[i]);
  }
}

// WnT[n][k]: node-half of [Wq | Wkv] QK cols; WeT[n][k]: edge-half.
// n<256 -> Q col n ; n>=256 -> K col n-256.
__global__ __launch_bounds__(256) void build_wnet(
    const float* __restrict__ Wq, const float* __restrict__ Wkv,
    bf16* __restrict__ WnT, bf16* __restrict__ WeT) {
  int n = blockIdx.x, k = threadIdx.x;
  float vn, ve;
  if (n < 256) {
    vn = Wq[(size_t)k * 256 + n];
    ve = Wq[(size_t)(256 + k) * 256 + n];
  } else {
    vn = Wkv[(size_t)k * 512 + (n - 256)];
    ve = Wkv[(size_t)(256 + k) * 512 + (n - 256)];
  }
  WnT[(size_t)n * 256 + k] = f2bf(vn);
  WeT[(size_t)n * 256 + k] = f2bf(ve);
}

// WcombT [256][2048] bf16 = per-head (Wv @ Wo), transposed.
// bias_vo[j] = sum_t Wkv_b[256+t]*Wo[t][j] + Wo_b[j].
__global__ __launch_bounds__(256) void build_wcomb(
    const float* __restrict__ Wkv, const float* __restrict__ Wkv_b,
    const float* __restrict__ Wo, const float* __restrict__ Wo_b,
    bf16* __restrict__ WcombT, float* __restrict__ bias_vo) {
  int j = blockIdx.x, t = threadIdx.x;
  __shared__ float wo[256];
  wo[t] = Wo[(size_t)t * 256 + j];
  __syncthreads();
#pragma unroll
  for (int p = 0; p < 8; ++p) {
    int idx = p * 256 + t;           // 0..2047
    int h = idx >> 9, i = idx & 511;
    const float* wrow = Wkv + (size_t)i * 512 + 256 + h * 64;
    const float* wob = wo + h * 64;
    float s = 0.f;
#pragma unroll 8
    for (int m = 0; m < 64; ++m) s += wrow[m] * wob[m];
    WcombT[(size_t)j * 2048 + idx] = f2bf(s);
  }
  float bs = Wkv_b[256 + t] * wo[t];
#pragma unroll
  for (int o = 32; o; o >>= 1) bs += __shfl_xor(bs, o);
  __shared__ float red[4];
  int wv = t >> 6, lane = t & 63;
  if (lane == 0) red[wv] = bs;
  __syncthreads();
  if (t == 0) bias_vo[j] = red[0] + red[1] + red[2] + red[3] + Wo_b[j];
}

__global__ __launch_bounds__(256) void count_deg(const int* __restrict__ src,
                                                 int* __restrict__ deg, int nE) {
  int e = blockIdx.x * 256 + threadIdx.x;
  if (e < nE) atomicAdd(&deg[src[e]], 1);
}

__global__ __launch_bounds__(256) void scan_offs(const int* __restrict__ deg,
                                                 int* __restrict__ offs,
                                                 int* __restrict__ cursor,
                                                 int nN) {
  __shared__ int part[256];
  int tid = threadIdx.x;
  int per = (nN + 255) >> 8;
  int lo = tid * per, hi = lo + per;
  if (hi > nN) hi = nN;
  int sm = 0;
  for (int i = lo; i < hi; ++i) sm += deg[i];
  part[tid] = sm;
  __syncthreads();
  if (tid == 0) {
    int run = 0;
    for (int i = 0; i < 256; ++i) {
      int v = part[i];
      part[i] = run;
      run += v;
    }
  }
  __syncthreads();
  int run = part[tid];
  for (int i = lo; i < hi; ++i) {
    offs[i] = run;
    cursor[i] = run;
    run += deg[i];
  }
  if (tid == 255) offs[nN] = run;
}

__global__ __launch_bounds__(256) void scatter_edges(const int* __restrict__ src,
                                                     int* __restrict__ cursor,
                                                     int* __restrict__ eperm,
                                                     int nE) {
  int e = blockIdx.x * 256 + threadIdx.x;
  if (e < nE) {
    int p = atomicAdd(&cursor[src[e]], 1);
    eperm[p] = e;
  }
}

// Per-node segment softmax + PER-HEAD weighted input aggregation.
// All edge streams sequential (CSR-permuted). Softmax weight for each
// (edge, head) computed ONCE by one thread into LDS, then broadcast.
// aggH[n][h*512 + c]     = sum_e w_e^h * h_n[dst_e][c]   (c<256)
// aggH[n][h*512 + 256+c] = sum_e w_e^h * h_e[e][c]
__global__ __launch_bounds__(256) void aggregate(
    const int* __restrict__ offs, const int* __restrict__ dp,
    const float* __restrict__ scores, const bf16* __restrict__ hn,
    const bf16* __restrict__ he, bf16* __restrict__ aggH) {
  int n = blockIdx.x;
  int s = offs[n];
  int deg = offs[n + 1] - s;
  int tid = threadIdx.x, wv = tid >> 6, lane = tid & 63;
  __shared__ float mdl[4], dnl[4];
  __shared__ float wl[64][4];
  // phase 1: wave wv owns head wv
  float mx = -3.4e38f;
  for (int i = lane; i < deg; i += 64)
    mx = fmaxf(mx, scores[(size_t)(s + i) * 4 + wv]);
#pragma unroll
  for (int o = 32; o; o >>= 1) mx = fmaxf(mx, __shfl_xor(mx, o));
  float sm = 0.f;
  for (int i = lane; i < deg; i += 64)
    sm += expf(scores[(size_t)(s + i) * 4 + wv] - mx);
#pragma unroll
  for (int o = 32; o; o >>= 1) sm += __shfl_xor(sm, o);
  if (lane == 0) {
    mdl[wv] = mx;
    dnl[wv] = sm;
  }
  __syncthreads();
  const float mh = mdl[wv];
  const float rdh = dnl[wv] > 0.f ? 1.f / dnl[wv] : 0.f;
  float accn[4] = {}, acce[4] = {};
  for (int c0 = 0; c0 < deg; c0 += 64) {
    int nc = deg - c0;
    if (nc > 64) nc = 64;
    // wave wv computes head-wv weights for the chunk's edges (1 expf each)
    if (lane < nc) {
      float sc = scores[(size_t)(s + c0 + lane) * 4 + wv];
      wl[lane][wv] = expf(sc - mh) * rdh;
    }
    __syncthreads();
    for (int i = 0; i < nc; ++i) {
      size_t p = (size_t)(s + c0 + i);
      int d = dp[p];
      float4 w4 = *(const float4*)wl[i];
      float xn = bf2f(hn[(size_t)d * 256 + tid]);
      float xe = bf2f(he[p * 256 + tid]);
      accn[0] += w4.x * xn; acce[0] += w4.x * xe;
      accn[1] += w4.y * xn; acce[1] += w4.y * xe;
      accn[2] += w4.z * xn; acce[2] += w4.z * xe;
      accn[3] += w4.w * xn; acce[3] += w4.w * xe;
    }
    __syncthreads();
  }
  bf16* out = aggH + (size_t)n * 2048;
#pragma unroll
  for (int h = 0; h < 4; ++h) {
    out[h * 512 + tid] = f2bf(accn[h]);
    out[h * 512 + 256 + tid] = f2bf(acce[h]);
  }
}

// y = LN(x1 + x2) * g + b ; optional f32 and bf16 outputs. block = row (256).
__global__ __launch_bounds__(256) void ln_kernel(
    const float* __restrict__ x1, const float* __restrict__ x2,
    const float* __restrict__ g, const float* __restrict__ b,
    float* __restrict__ outf, bf16* __restrict__ outb) {
  int n = blockIdx.x, tid = threadIdx.x;
  float x = x1[(size_t)n * 256 + tid] + x2[(size_t)n * 256 + tid];
  float s = x, s2 = x * x;
#pragma unroll
  for (int o = 32; o; o >>= 1) {
    s += __shfl_xor(s, o);
    s2 += __shfl_xor(s2, o);
  }
  __shared__ float ls[4], ls2[4];
  int wv = tid >> 6, lane = tid & 63;
  if (lane == 0) {
    ls[wv] = s;
    ls2[wv] = s2;
  }
  __syncthreads();
  s = ls[0] + ls[1] + ls[2] + ls[3];
  s2 = ls2[0] + ls2[1] + ls2[2] + ls2[3];
  float mu = s * (1.f / 256.f);
  float var = s2 * (1.f / 256.f) - mu * mu;
  float y = (x - mu) * rsqrtf(var + 1e-5f) * g[tid] + b[tid];
  if (outf) outf[(size_t)n * 256 + tid] = y;
  if (outb) outb[(size_t)n * 256 + tid] = f2bf(y);
}

// --------------------------- workspace layout ------------------------------
static constexpr size_t OFF_HN    = 0;                     // 50000*256 bf16
static constexpr size_t OFF_HE    = 25600000;              // 400000*256 bf16 (CSR order)
static constexpr size_t OFF_WNT   = 230400000;             // 512x256 bf16
static constexpr size_t OFF_WET   = 230662144;             // 512x256 bf16
static constexpr size_t OFF_WCT   = 230924288;             // 256x2048 bf16
static constexpr size_t OFF_W1T   = 231972864;             // 1024x256 bf16
static constexpr size_t OFF_W2T   = 232497152;             // 256x1024 bf16
static constexpr size_t OFF_BVO   = 233021440;             // 256 f32
static constexpr size_t OFF_SC    = 233022464;             // 400000*4 f32
static constexpr size_t OFF_DEG   = 239422464;             // 50000 i32
static constexpr size_t OFF_OFFS  = 239622464;             // 50001 i32 (padded)
static constexpr size_t OFF_CUR   = 239822528;             // 50000 i32
static constexpr size_t OFF_EPERM = 240022528;             // 400000 i32
static constexpr size_t OFF_SP    = 241622528;             // 400000 i32
static constexpr size_t OFF_DP    = 243222528;             // 400000 i32
static constexpr size_t OFF_ENF   = 244822528;             // 50000*512 f32
static constexpr size_t OFF_AGGH  = 347222528;             // 50000*2048 bf16
// aliases (stream-ordered): he dead after aggregate; aggH dead after VO GEMM.
static constexpr size_t OFF_TMP   = OFF_HE;                // 50000*256 f32
static constexpr size_t OFF_H1F   = OFF_HE + 51200000;     // 50000*256 f32
static constexpr size_t OFF_H1B   = OFF_HE + 102400000;    // 50000*256 bf16
static constexpr size_t OFF_TMP2  = OFF_HE + 128000000;    // 50000*256 f32
static constexpr size_t OFF_FFM   = OFF_AGGH;              // 50000*1024 bf16
// total need: OFF_AGGH + 204800000 = 552,022,528 bytes

extern "C" void kernel_launch(void* const* d_in, const int* in_sizes, int n_in,
                              void* d_out, int out_size, void* d_ws,
                              size_t ws_size, hipStream_t stream) {
  const float* h_n = (const float*)d_in[0];
  const float* h_e = (const float*)d_in[1];
  const int* eidx = (const int*)d_in[2];
  const int* src = eidx;
  const int* dst = eidx + NE;
  const float* Wq_w = (const float*)d_in[3];
  const float* Wq_b = (const float*)d_in[4];
  const float* Wkv_w = (const float*)d_in[5];
  const float* Wkv_b = (const float*)d_in[6];
  const float* Wo_w = (const float*)d_in[7];
  const float* Wo_b = (const float*)d_in[8];
  const float* ln1_g = (const float*)d_in[9];
  const float* ln1_b = (const float*)d_in[10];
  const float* f1_w = (const float*)d_in[11];
  const float* f1_b = (const float*)d_in[12];
  const float* f2_w = (const float*)d_in[13];
  const float* f2_b = (const float*)d_in[14];
  const float* ln2_g = (const float*)d_in[15];
  const float* ln2_b = (const float*)d_in[16];

  uint8_t* ws = (uint8_t*)d_ws;
  bf16* hn_bf = (bf16*)(ws + OFF_HN);
  bf16* he_bf = (bf16*)(ws + OFF_HE);
  bf16* WnT = (bf16*)(ws + OFF_WNT);
  bf16* WeT = (bf16*)(ws + OFF_WET);
  bf16* WcombT = (bf16*)(ws + OFF_WCT);
  bf16* W1T = (bf16*)(ws + OFF_W1T);
  bf16* W2T = (bf16*)(ws + OFF_W2T);
  float* bias_vo = (float*)(ws + OFF_BVO);
  float* scores = (float*)(ws + OFF_SC);
  int* deg = (int*)(ws + OFF_DEG);
  int* offs = (int*)(ws + OFF_OFFS);
  int* cursor = (int*)(ws + OFF_CUR);
  int* eperm = (int*)(ws + OFF_EPERM);
  int* sp = (int*)(ws + OFF_SP);
  int* dp = (int*)(ws + OFF_DP);
  float* ENf = (float*)(ws + OFF_ENF);
  bf16* aggH = (bf16*)(ws + OFF_AGGH);
  float* tmp = (float*)(ws + OFF_TMP);
  float* h1f = (float*)(ws + OFF_H1F);
  bf16* h1b = (bf16*)(ws + OFF_H1B);
  float* tmp2 = (float*)(ws + OFF_TMP2);
  bf16* ffm = (bf16*)(ws + OFF_FFM);

  // 1. node cast + weight prep
  cast_bf16<<<12500, 256, 0, stream>>>(h_n, hn_bf, NN * 256);
  build_wnet<<<512, 256, 0, stream>>>(Wq_w, Wkv_w, WnT, WeT);
  build_wcomb<<<256, 256, 0, stream>>>(Wkv_w, Wkv_b, Wo_w, Wo_b, WcombT,
                                       bias_vo);
  transpose_cast<<<1024, 256, 0, stream>>>(f1_w, W1T, 256, 1024);
  transpose_cast<<<1024, 256, 0, stream>>>(f2_w, W2T, 1024, 256);

  // 2. CSR over src, then permuted edge streams
  hipMemsetAsync(deg, 0, NN * sizeof(int), stream);
  count_deg<<<1563, 256, 0, stream>>>(src, deg, NE);
  scan_offs<<<1, 256, 0, stream>>>(deg, offs, cursor, NN);
  scatter_edges<<<1563, 256, 0, stream>>>(src, cursor, eperm, NE);
  perm_sd<<<1563, 256, 0, stream>>>(src, dst, eperm, sp, dp, NE);
  cast_he_perm<<<100000, 256, 0, stream>>>(h_e, eperm, he_bf);

  // 3. node QK table (f32), then fused edge Q/K + scores (Q,K stay in regs)
  gemm_node<256, 0><<<dim3(4, 391), 256, 0, stream>>>(hn_bf, NN, WnT, nullptr,
                                                      512, ENf, nullptr);
  gemm_qk<<<dim3(2, 3125), 256, 0, stream>>>(he_bf, WeT, WeT + 256 * 256, Wq_b,
                                             Wkv_b, sp, dp, ENf, scores);

  // 4. segment softmax + per-head weighted input aggregation (sequential)
  aggregate<<<NN, 256, 0, stream>>>(offs, dp, scores, hn_bf, he_bf, aggH);

  // 5. folded V-projection + Wo (one K=2048 GEMM) + LN1
  gemm_node<2048, 0><<<dim3(2, 391), 256, 0, stream>>>(aggH, NN, WcombT,
                                                       bias_vo, 256, tmp,
                                                       nullptr);
  ln_kernel<<<NN, 256, 0, stream>>>(h_n, tmp, ln1_g, ln1_b, h1f, h1b);

  // 6. FFN + LN2
  gemm_node<256, 1><<<dim3(8, 391), 256, 0, stream>>>(h1b, NN, W1T, f1_b, 1024,
                                                      nullptr, ffm);
  gemm_node<1024, 0><<<dim3(2, 391), 256, 0, stream>>>(ffm, NN, W2T, f2_b, 256,
                                                       tmp2, nullptr);
  ln_kernel<<<NN, 256, 0, stream>>>(h1f, tmp2, ln2_g, ln2_b, (float*)d_out,
                                    nullptr);
}